// Round 1
// baseline (479.378 us; speedup 1.0000x reference)
//
#include <hip/hip_runtime.h>

#define BATCH 16
#define CH    64
#define LEN   4096
#define NCODE 1024
#define NPTS  (BATCH * LEN)   // 65536

// ---------------------------------------------------------------------------
// Kernel 1: w2[k] = sum_c codebook[k,c]^2
// ---------------------------------------------------------------------------
__global__ __launch_bounds__(256) void vq_w2(const float* __restrict__ cb,
                                             float* __restrict__ w2) {
    int k = blockIdx.x * 256 + threadIdx.x;
    if (k < NCODE) {
        const float* w = cb + (size_t)k * CH;
        float s = 0.f;
#pragma unroll
        for (int c = 0; c < CH; ++c) s = fmaf(w[c], w[c], s);
        w2[k] = s;
    }
}

// ---------------------------------------------------------------------------
// Kernel 2: per-point argmin over the codebook.
// Block = 256 threads = 64 points x 4 K-slices (each slice scans 256 codes).
// Codebook accesses are wave-uniform -> scalar loads (constant cache), the
// inner loop is pure v_fmac_f32 with one SGPR operand.
// ---------------------------------------------------------------------------
__global__ __launch_bounds__(256) void vq_argmin(const float*  __restrict__ x,
                                                 const float*  __restrict__ cb,
                                                 const float*  __restrict__ w2,
                                                 float*        __restrict__ idx_out,
                                                 double*       __restrict__ partial) {
    const int t     = threadIdx.x;
    const int pt    = t & 63;        // point within block
    const int slice = t >> 6;        // 0..3 K-slice
    const int p     = blockIdx.x * 64 + pt;   // global point id
    const int b     = p >> 12;       // / LEN
    const int l     = p & (LEN - 1);

    // Load this point's 64 channels into registers (coalesced across lanes).
    const float* xb = x + (size_t)b * CH * LEN + l;
    float xr[CH];
#pragma unroll
    for (int c = 0; c < CH; ++c) xr[c] = xb[(size_t)c * LEN];

    float x2 = 0.f;
#pragma unroll
    for (int c = 0; c < CH; ++c) x2 = fmaf(xr[c], xr[c], x2);

    const int k0 = slice * (NCODE / 4);
    float best  = 3.4e38f;
    int   bestk = k0;

    for (int k = k0; k < k0 + NCODE / 4; ++k) {
        const float* w = cb + (size_t)k * CH;   // wave-uniform address
        float a0 = 0.f, a1 = 0.f, a2 = 0.f, a3 = 0.f;
#pragma unroll
        for (int c = 0; c < CH; c += 4) {
            a0 = fmaf(xr[c + 0], w[c + 0], a0);
            a1 = fmaf(xr[c + 1], w[c + 1], a1);
            a2 = fmaf(xr[c + 2], w[c + 2], a2);
            a3 = fmaf(xr[c + 3], w[c + 3], a3);
        }
        float dot = (a0 + a1) + (a2 + a3);
        float d2  = (x2 - 2.0f * dot) + w2[k];
        if (d2 < best) { best = d2; bestk = k; }   // strict < = first-occurrence
    }

    __shared__ float  sbest[256];
    __shared__ int    skid[256];
    __shared__ double ssum[64];
    sbest[t] = best;
    skid[t]  = bestk;
    __syncthreads();

    if (slice == 0) {
        // Combine the 4 K-slices in ascending-k order (preserves argmin ties).
#pragma unroll
        for (int s = 1; s < 4; ++s) {
            float ob = sbest[pt + 64 * s];
            int   ok = skid[pt + 64 * s];
            if (ob < best) { best = ob; bestk = ok; }
        }
        idx_out[p] = (float)bestk;
        ssum[pt]   = (double)best;   // min d2 == ||x - quant||^2
    }
    __syncthreads();

    if (t == 0) {
        double s = 0.0;
        for (int i = 0; i < 64; ++i) s += ssum[i];
        partial[blockIdx.x] = s;
    }
}

// ---------------------------------------------------------------------------
// Kernel 3: quant_out[b,c,l] = codebook[idx[b,l], c]  (coalesced writes)
// ---------------------------------------------------------------------------
__global__ __launch_bounds__(256) void vq_gather(const float* __restrict__ cb,
                                                 const float* __restrict__ idx_f,
                                                 float*       __restrict__ out) {
    int t  = blockIdx.x * 256 + threadIdx.x;   // over B*C*L
    int l  = t & (LEN - 1);
    int bc = t >> 12;
    int c  = bc & (CH - 1);
    int b  = bc >> 6;
    int k  = (int)idx_f[b * LEN + l];
    out[t] = cb[(size_t)k * CH + c];
}

// ---------------------------------------------------------------------------
// Kernel 4: final loss reduction over the 1024 per-block partials.
// ---------------------------------------------------------------------------
__global__ __launch_bounds__(256) void vq_loss(const double* __restrict__ partial,
                                               float*        __restrict__ losses) {
    __shared__ double sred[256];
    double v = 0.0;
#pragma unroll
    for (int i = 0; i < 4; ++i) v += partial[threadIdx.x + 256 * i];
    sred[threadIdx.x] = v;
    __syncthreads();
    for (int s = 128; s > 0; s >>= 1) {
        if (threadIdx.x < s) sred[threadIdx.x] += sred[threadIdx.x + s];
        __syncthreads();
    }
    if (threadIdx.x == 0) {
        float loss = (float)(sred[0] / (double)((size_t)NPTS * CH));
        losses[0] = loss;   // codebook_loss
        losses[1] = loss;   // commitment_loss (same value)
    }
}

// ---------------------------------------------------------------------------
extern "C" void kernel_launch(void* const* d_in, const int* in_sizes, int n_in,
                              void* d_out, int out_size, void* d_ws, size_t ws_size,
                              hipStream_t stream) {
    const float* x  = (const float*)d_in[0];   // (B, C, L)
    const float* cb = (const float*)d_in[1];   // (K, C)
    float* out = (float*)d_out;

    // d_out layout: [quant_out (B*C*L)] [codebook_loss] [commitment_loss] [indices (B*L)]
    float* quant_out = out;
    float* losses    = out + (size_t)BATCH * CH * LEN;
    float* idx_out   = losses + 2;

    // workspace: [0, 8KB): double partial sums (1024); [8KB, 12KB): w2 (1024 floats)
    double* partial = (double*)d_ws;
    float*  w2      = (float*)((char*)d_ws + 8192);

    vq_w2<<<NCODE / 256, 256, 0, stream>>>(cb, w2);
    vq_argmin<<<NPTS / 64, 256, 0, stream>>>(x, cb, w2, idx_out, partial);
    vq_gather<<<(BATCH * CH * LEN) / 256, 256, 0, stream>>>(cb, idx_out, quant_out);
    vq_loss<<<1, 256, 0, stream>>>(partial, losses);
}

// Round 2
// 166.104 us; speedup vs baseline: 2.8860x; 2.8860x over previous
//
#include <hip/hip_runtime.h>

#define BATCH 16
#define CH    64
#define LEN   4096
#define NCODE 1024
#define NPTS  (BATCH * LEN)   // 65536

// ---------------------------------------------------------------------------
// Kernel 1: w2[k] = sum_c codebook[k,c]^2
// ---------------------------------------------------------------------------
__global__ __launch_bounds__(256) void vq_w2(const float* __restrict__ cb,
                                             float* __restrict__ w2) {
    int k = blockIdx.x * 256 + threadIdx.x;
    if (k < NCODE) {
        const float* w = cb + (size_t)k * CH;
        float s = 0.f;
#pragma unroll
        for (int c = 0; c < CH; ++c) s = fmaf(w[c], w[c], s);
        w2[k] = s;
    }
}

// ---------------------------------------------------------------------------
// Kernel 2: per-point argmin over the codebook.
// Block = 256 threads = 64 points x 4 K-slices (each slice scans 256 codes).
// slice is forced scalar via readfirstlane so the codebook address chain is
// provably wave-uniform -> s_load_dwordx16 into SGPRs, inner loop is pure
// v_fmac_f32 v, s, v (SMEM pipe never touches VALU issue slots).
// ---------------------------------------------------------------------------
__global__ __launch_bounds__(256, 1) void vq_argmin(const float*  __restrict__ x,
                                                    const float*  __restrict__ cb,
                                                    const float*  __restrict__ w2,
                                                    float*        __restrict__ idx_out,
                                                    double*       __restrict__ partial) {
    const int t     = threadIdx.x;
    const int pt    = t & 63;                                  // point within block
    const int slice = __builtin_amdgcn_readfirstlane(t >> 6);  // 0..3, provably scalar
    const int p     = blockIdx.x * 64 + pt;                    // global point id
    const int b     = p >> 12;                                 // / LEN
    const int l     = p & (LEN - 1);

    // Load this point's 64 channels into registers (coalesced across lanes).
    const float* xb = x + (size_t)b * CH * LEN + l;
    float xr[CH];
#pragma unroll
    for (int c = 0; c < CH; ++c) xr[c] = xb[(size_t)c * LEN];

    float x2 = 0.f;
#pragma unroll
    for (int c = 0; c < CH; ++c) x2 = fmaf(xr[c], xr[c], x2);

    const float* __restrict__ wp  = cb + (size_t)slice * (NCODE / 4) * CH; // scalar ptr
    const float* __restrict__ w2p = w2 + slice * (NCODE / 4);              // scalar ptr

    float best  = 3.4e38f;
    int   bestk = 0;

    for (int k = 0; k < NCODE / 4; ++k) {
        const float* w = wp + (size_t)k * CH;   // scalar (uniform loop counter)
        float a0 = 0.f, a1 = 0.f, a2 = 0.f, a3 = 0.f;
#pragma unroll
        for (int c = 0; c < CH; c += 4) {
            a0 = fmaf(xr[c + 0], w[c + 0], a0);
            a1 = fmaf(xr[c + 1], w[c + 1], a1);
            a2 = fmaf(xr[c + 2], w[c + 2], a2);
            a3 = fmaf(xr[c + 3], w[c + 3], a3);
        }
        float dot = (a0 + a1) + (a2 + a3);
        float d2  = (x2 - 2.0f * dot) + w2p[k];
        if (d2 < best) { best = d2; bestk = k; }   // strict < = first-occurrence
    }
    bestk += slice * (NCODE / 4);

    __shared__ float  sbest[256];
    __shared__ int    skid[256];
    __shared__ double ssum[64];
    sbest[t] = best;
    skid[t]  = bestk;
    __syncthreads();

    if (slice == 0) {
        // Combine the 4 K-slices in ascending-k order (preserves argmin ties).
#pragma unroll
        for (int s = 1; s < 4; ++s) {
            float ob = sbest[pt + 64 * s];
            int   ok = skid[pt + 64 * s];
            if (ob < best) { best = ob; bestk = ok; }
        }
        idx_out[p] = (float)bestk;
        ssum[pt]   = (double)best;   // min d2 == ||x - quant||^2
    }
    __syncthreads();

    if (t == 0) {
        double s = 0.0;
        for (int i = 0; i < 64; ++i) s += ssum[i];
        partial[blockIdx.x] = s;
    }
}

// ---------------------------------------------------------------------------
// Kernel 3: quant_out[b,c,l] = codebook[idx[b,l], c]  (coalesced writes)
// ---------------------------------------------------------------------------
__global__ __launch_bounds__(256) void vq_gather(const float* __restrict__ cb,
                                                 const float* __restrict__ idx_f,
                                                 float*       __restrict__ out) {
    int t  = blockIdx.x * 256 + threadIdx.x;   // over B*C*L
    int l  = t & (LEN - 1);
    int bc = t >> 12;
    int c  = bc & (CH - 1);
    int b  = bc >> 6;
    int k  = (int)idx_f[b * LEN + l];
    out[t] = cb[(size_t)k * CH + c];
}

// ---------------------------------------------------------------------------
// Kernel 4: final loss reduction over the 1024 per-block partials.
// ---------------------------------------------------------------------------
__global__ __launch_bounds__(256) void vq_loss(const double* __restrict__ partial,
                                               float*        __restrict__ losses) {
    __shared__ double sred[256];
    double v = 0.0;
#pragma unroll
    for (int i = 0; i < 4; ++i) v += partial[threadIdx.x + 256 * i];
    sred[threadIdx.x] = v;
    __syncthreads();
    for (int s = 128; s > 0; s >>= 1) {
        if (threadIdx.x < s) sred[threadIdx.x] += sred[threadIdx.x + s];
        __syncthreads();
    }
    if (threadIdx.x == 0) {
        float loss = (float)(sred[0] / (double)((size_t)NPTS * CH));
        losses[0] = loss;   // codebook_loss
        losses[1] = loss;   // commitment_loss (same value)
    }
}

// ---------------------------------------------------------------------------
extern "C" void kernel_launch(void* const* d_in, const int* in_sizes, int n_in,
                              void* d_out, int out_size, void* d_ws, size_t ws_size,
                              hipStream_t stream) {
    const float* x  = (const float*)d_in[0];   // (B, C, L)
    const float* cb = (const float*)d_in[1];   // (K, C)
    float* out = (float*)d_out;

    // d_out layout: [quant_out (B*C*L)] [codebook_loss] [commitment_loss] [indices (B*L)]
    float* quant_out = out;
    float* losses    = out + (size_t)BATCH * CH * LEN;
    float* idx_out   = losses + 2;

    // workspace: [0, 8KB): double partial sums (1024); [8KB, 12KB): w2 (1024 floats)
    double* partial = (double*)d_ws;
    float*  w2      = (float*)((char*)d_ws + 8192);

    vq_w2<<<NCODE / 256, 256, 0, stream>>>(cb, w2);
    vq_argmin<<<NPTS / 64, 256, 0, stream>>>(x, cb, w2, idx_out, partial);
    vq_gather<<<(BATCH * CH * LEN) / 256, 256, 0, stream>>>(cb, idx_out, quant_out);
    vq_loss<<<1, 256, 0, stream>>>(partial, losses);
}